// Round 1
// baseline (802.399 us; speedup 1.0000x reference)
//
#include <hip/hip_runtime.h>

namespace {
constexpr int Bb = 8, Cc = 256, Hh = 64, Ww = 64, Oo = 256, K2c = 9;
constexpr int HW = Hh * Ww;
constexpr int BM = 128;            // output-channel tile
constexpr int BN = 128;            // position tile = 2 rows x 64 cols
constexpr int NT = 256;            // threads per block
constexpr int META = K2c * BN;     // 1152 (k,pos) sampling slots
constexpr int CK = Cc * K2c;       // 2304 = GEMM K
}

// 128x128 tile, 8x8 per-thread register tile, double-buffered LDS,
// software-pipelined channel loop (issue gathers c+1 while computing c).
__global__ __launch_bounds__(NT, 2)
void dcn_fp32(const float* __restrict__ inp,
              const float* __restrict__ offset,
              const float* __restrict__ mask,
              const float* __restrict__ weight,
              const float* __restrict__ bias,
              float* __restrict__ out) {
  __shared__ __align__(16) float4 mw[META];   // bilinear weights * mask (4 corners)
  __shared__ __align__(16) int4   mi[META];   // clipped flat indices (4 corners)
  __shared__ __align__(16) float  Sl[2][META]; // sampled tile  [k][pos]
  __shared__ __align__(16) float  Wl[2][META]; // weight tile   [k][o_local]

  const int tid = threadIdx.x;
  const int og  = blockIdx.x;  // 0..1   output-channel group
  const int rp  = blockIdx.y;  // 0..31  row pair
  const int b   = blockIdx.z;  // 0..7   batch

  // ---- phase 1: per-(k,pos) sampling metadata ----
#pragma unroll
  for (int n = 0; n < 5; ++n) {
    int t = tid + n * NT;
    if (t < META) {
      int k = t >> 7, pos = t & 127;
      int r = pos >> 6, wo = pos & 63;
      int ho = rp * 2 + r;
      const float offy = offset[((b * 2 * K2c + 2 * k)     * Hh + ho) * Ww + wo];
      const float offx = offset[((b * 2 * K2c + 2 * k + 1) * Hh + ho) * Ww + wo];
      const float m    = mask  [((b * K2c + k)             * Hh + ho) * Ww + wo];
      const int ki = k / 3, kj = k % 3;
      float y = offy + (float)(ho - 1 + ki);
      float x = offx + (float)(wo - 1 + kj);
      float y0f = floorf(y), x0f = floorf(x);
      float ly = y - y0f, lx = x - x0f;
      float hy = 1.f - ly, hx = 1.f - lx;
      int y0 = (int)y0f, x0 = (int)x0f;
      int y1 = y0 + 1, x1 = x0 + 1;
      bool vy0 = (y0 >= 0) && (y0 < Hh);
      bool vy1 = (y1 >= 0) && (y1 < Hh);
      bool vx0 = (x0 >= 0) && (x0 < Ww);
      bool vx1 = (x1 >= 0) && (x1 < Ww);
      int cy0 = min(max(y0, 0), Hh - 1), cy1 = min(max(y1, 0), Hh - 1);
      int cx0 = min(max(x0, 0), Ww - 1), cx1 = min(max(x1, 0), Ww - 1);
      float4 w4;
      w4.x = (vy0 && vx0) ? hy * hx * m : 0.f;
      w4.y = (vy0 && vx1) ? hy * lx * m : 0.f;
      w4.z = (vy1 && vx0) ? ly * hx * m : 0.f;
      w4.w = (vy1 && vx1) ? ly * lx * m : 0.f;
      int4 i4;
      i4.x = cy0 * Ww + cx0; i4.y = cy0 * Ww + cx1;
      i4.z = cy1 * Ww + cx0; i4.w = cy1 * Ww + cx1;
      mw[t] = w4;
      mi[t] = i4;
    }
  }
  __syncthreads();

  const float* __restrict__ plane0 = inp + (size_t)b * Cc * HW;
  const float* __restrict__ wbase  = weight + (size_t)og * BM * CK;

  float gv[5][4];  // gathered corners for channel-in-flight
  float gw[5];     // weight values in-flight

  // prologue: issue gathers for c = 0
  {
    const float* pl = plane0;
#pragma unroll
    for (int n = 0; n < 5; ++n) {
      int t = tid + n * NT;
      if (t < META) {
        int4 i4 = mi[t];
        gv[n][0] = pl[i4.x]; gv[n][1] = pl[i4.y];
        gv[n][2] = pl[i4.z]; gv[n][3] = pl[i4.w];
        gw[n] = wbase[(t / 9) * CK + (t % 9)];
      }
    }
  }

  float acc[8][8];
#pragma unroll
  for (int i = 0; i < 8; ++i)
#pragma unroll
    for (int j = 0; j < 8; ++j) acc[i][j] = 0.f;

  const int to = tid >> 4;   // 0..15 -> 8 outputs each
  const int tp = tid & 15;   // 0..15 -> 8 positions each
  int buf = 0;

  for (int c = 0; c < Cc; ++c) {
    // commit channel c into LDS
#pragma unroll
    for (int n = 0; n < 5; ++n) {
      int t = tid + n * NT;
      if (t < META) {
        float4 w4 = mw[t];
        Sl[buf][t] = w4.x * gv[n][0] + w4.y * gv[n][1] +
                     w4.z * gv[n][2] + w4.w * gv[n][3];
        Wl[buf][(t % 9) * BM + (t / 9)] = gw[n];
      }
    }
    __syncthreads();

    // issue gathers for channel c+1 (lands during compute below)
    if (c + 1 < Cc) {
      const float* pl = plane0 + (size_t)(c + 1) * HW;
#pragma unroll
      for (int n = 0; n < 5; ++n) {
        int t = tid + n * NT;
        if (t < META) {
          int4 i4 = mi[t];
          gv[n][0] = pl[i4.x]; gv[n][1] = pl[i4.y];
          gv[n][2] = pl[i4.z]; gv[n][3] = pl[i4.w];
          gw[n] = wbase[(t / 9) * CK + (size_t)(c + 1) * K2c + (t % 9)];
        }
      }
    }

    // 8x8 outer-product FMA over the 9 kernel taps
#pragma unroll
    for (int kk = 0; kk < K2c; ++kk) {
      const float4* wr4 = (const float4*)&Wl[buf][kk * BM];
      const float4* sr4 = (const float4*)&Sl[buf][kk * BN];
      float4 w0 = wr4[to * 2], w1 = wr4[to * 2 + 1];
      float4 s0 = sr4[tp * 2], s1 = sr4[tp * 2 + 1];
      float wr[8] = { w0.x, w0.y, w0.z, w0.w, w1.x, w1.y, w1.z, w1.w };
      float sr[8] = { s0.x, s0.y, s0.z, s0.w, s1.x, s1.y, s1.z, s1.w };
#pragma unroll
      for (int i = 0; i < 8; ++i)
#pragma unroll
        for (int j = 0; j < 8; ++j)
          acc[i][j] += wr[i] * sr[j];
    }
    buf ^= 1;
  }

  // ---- epilogue: bias + store ----
  const int row = tp >> 3;          // 0 or 1
  const int wo0 = (tp * 8) & 63;    // starting column
  const int ho  = rp * 2 + row;
#pragma unroll
  for (int i = 0; i < 8; ++i) {
    int o = og * BM + to * 8 + i;
    float bv = bias[o];
    float* op = out + (((size_t)b * Oo + o) * Hh + ho) * Ww + wo0;
    float4 v0 = { acc[i][0] + bv, acc[i][1] + bv, acc[i][2] + bv, acc[i][3] + bv };
    float4 v1 = { acc[i][4] + bv, acc[i][5] + bv, acc[i][6] + bv, acc[i][7] + bv };
    *(float4*)(op)     = v0;
    *(float4*)(op + 4) = v1;
  }
}

extern "C" void kernel_launch(void* const* d_in, const int* in_sizes, int n_in,
                              void* d_out, int out_size, void* d_ws, size_t ws_size,
                              hipStream_t stream) {
  const float* inp    = (const float*)d_in[0];
  const float* offset = (const float*)d_in[1];
  const float* mask   = (const float*)d_in[2];
  const float* weight = (const float*)d_in[3];
  const float* bias   = (const float*)d_in[4];
  float* out = (float*)d_out;
  dim3 grid(Oo / BM, Hh / 2, Bb);   // (2, 32, 8)
  hipLaunchKernelGGL(dcn_fp32, grid, dim3(NT), 0, stream,
                     inp, offset, mask, weight, bias, out);
}

// Round 2
// 210.277 us; speedup vs baseline: 3.8159x; 3.8159x over previous
//
#include <hip/hip_runtime.h>

typedef _Float16 f16x8 __attribute__((ext_vector_type(8)));
typedef float    f32x4 __attribute__((ext_vector_type(4)));

namespace {
constexpr int Bb = 8, Cc = 256, Oo = 256, K2 = 9;
constexpr int HW = 4096;                 // 64x64
constexpr int CK = 2304;                 // GEMM K
constexpr int NCHUNK = 72;               // 2304 / 32
}

__device__ inline f16x8 sp8(_Float16 x) { f16x8 r = {x,x,x,x,x,x,x,x}; return r; }

// ---------- pre-kernel 1: NCHW fp32 -> NHWC fp16 ----------
__global__ __launch_bounds__(256)
void nchw_to_nhwc_f16(const float* __restrict__ in, _Float16* __restrict__ outh) {
  __shared__ _Float16 Lt[64][264];   // [px][c], padded for 16B-aligned rows
  const int t   = threadIdx.x;
  const int hw0 = blockIdx.x * 64;
  const int b   = blockIdx.y;
  const float* src = in + (size_t)b * Cc * HW + hw0;
  for (int ci = 0; ci < 64; ++ci) {          // 4 channels x 64 px per iter
    int cc = ci * 4 + (t >> 6);
    int px = t & 63;
    Lt[px][cc] = (_Float16)src[(size_t)cc * HW + px];
  }
  __syncthreads();
  _Float16* dst = outh + ((size_t)b * HW + hw0) * Cc;
  for (int it = 0; it < 8; ++it) {           // 8 px x 32 threads per iter
    int px = it * 8 + (t >> 5);
    int c8 = (t & 31) * 8;
    f16x8 v;
#pragma unroll
    for (int j = 0; j < 8; ++j) v[j] = Lt[px][c8 + j];
    *(f16x8*)(dst + (size_t)px * Cc + c8) = v;
  }
}

// ---------- pre-kernel 2: weight fp32 [O][C][9] -> fp16 [chunk][kq][o][k8], K = tap*256+c ----------
__global__ __launch_bounds__(256)
void wcvt(const float* __restrict__ w, _Float16* __restrict__ wh) {
  int i = blockIdx.x * 256 + threadIdx.x;    // i = o*2304 + c*9 + tap (coalesced read)
  int o = i / 2304;
  int r = i - o * 2304;
  int c = r / 9;
  int tap = r - c * 9;
  int K = tap * 256 + c;
  int dst = (K >> 5) * 8192 + ((K >> 3) & 3) * 2048 + o * 8 + (K & 7);
  wh[dst] = (_Float16)w[i];
}

// ---------- main kernel: 256x128 tile, fp16 MFMA implicit GEMM ----------
__global__ __launch_bounds__(512, 2)
void dcn_mfma(const _Float16* __restrict__ inh,   // [B][4096][256] fp16
              const _Float16* __restrict__ wgh,   // [72][4][256][8] fp16
              const float* __restrict__ offset,
              const float* __restrict__ mask,
              const float* __restrict__ bias,
              float* __restrict__ out) {
  __shared__ __align__(16) int4     mi4[1152];   // 4 corner pixel indices per (tap,pos)
  __shared__ __align__(16) float4   mw4[1152];   // 4 corner weights (validity+mask folded)
  __shared__ __align__(16) _Float16 Wl[8192];    // [kq][256 o][8 k]  (16 KB)
  __shared__ __align__(16) _Float16 Sl[4096];    // [kq][128 p][8 k]  (8 KB)
  __shared__ float bias_l[256];

  const int tid = threadIdx.x;
  const int rp  = blockIdx.x;   // 0..31 : 2 output rows
  const int b   = blockIdx.y;   // 0..7

  if (tid < 256) bias_l[tid] = bias[tid];

  // ---- metadata: 1152 (tap,pos) entries ----
#pragma unroll
  for (int n = 0; n < 3; ++n) {
    int idx = tid + n * 512;
    if (idx < 1152) {
      int k = idx >> 7, p = idx & 127;
      int r = p >> 6, wo = p & 63;
      int ho = rp * 2 + r;
      float offy = offset[(((size_t)b * 18 + 2 * k)     * 64 + ho) * 64 + wo];
      float offx = offset[(((size_t)b * 18 + 2 * k + 1) * 64 + ho) * 64 + wo];
      float m    = mask  [(((size_t)b * 9  + k)         * 64 + ho) * 64 + wo];
      int ki = k / 3, kj = k % 3;
      float y = offy + (float)(ho - 1 + ki);
      float x = offx + (float)(wo - 1 + kj);
      float y0f = floorf(y), x0f = floorf(x);
      float ly = y - y0f, lx = x - x0f;
      float hy = 1.f - ly, hx = 1.f - lx;
      int y0 = (int)y0f, x0 = (int)x0f;
      int y1 = y0 + 1, x1 = x0 + 1;
      bool vy0 = (unsigned)y0 < 64u, vy1 = (unsigned)y1 < 64u;
      bool vx0 = (unsigned)x0 < 64u, vx1 = (unsigned)x1 < 64u;
      int cy0 = min(max(y0, 0), 63), cy1 = min(max(y1, 0), 63);
      int cx0 = min(max(x0, 0), 63), cx1 = min(max(x1, 0), 63);
      float4 w4;
      w4.x = (vy0 && vx0) ? hy * hx * m : 0.f;
      w4.y = (vy0 && vx1) ? hy * lx * m : 0.f;
      w4.z = (vy1 && vx0) ? ly * hx * m : 0.f;
      w4.w = (vy1 && vx1) ? ly * lx * m : 0.f;
      mi4[idx] = make_int4(cy0 * 64 + cx0, cy0 * 64 + cx1, cy1 * 64 + cx0, cy1 * 64 + cx1);
      mw4[idx] = w4;
    }
  }
  __syncthreads();

  // ---- thread roles ----
  const int p  = tid & 127;        // position within tile (sampling)
  const int cg = tid >> 7;         // channel-octet group 0..3 (sampling)
  const int lane = tid & 63, wid = tid >> 6;
  const int wm = wid >> 1, wn = wid & 1;          // wave tile: 64(o) x 64(p)
  const int lq = lane >> 4, lr = lane & 15;

  const f16x8* gin = (const f16x8*)(inh + (size_t)b * HW * Cc);
  const uint4* wg4 = (const uint4*)wgh;

  f16x8 v0, v1, v2, v3; float4 w4r; uint4 wv0, wv1;

  // prefetch chunk 0
  {
    int midx = 0 * 128 + p;
    int4 px = mi4[midx]; w4r = mw4[midx];
    int cb8 = (0 * 32 + cg * 8) >> 3;
    v0 = gin[px.x * 32 + cb8]; v1 = gin[px.y * 32 + cb8];
    v2 = gin[px.z * 32 + cb8]; v3 = gin[px.w * 32 + cb8];
    wv0 = wg4[tid]; wv1 = wg4[512 + tid];
  }

  f32x4 acc[4][4];
#pragma unroll
  for (int mt = 0; mt < 4; ++mt)
#pragma unroll
    for (int nt = 0; nt < 4; ++nt) { acc[mt][nt][0]=0.f; acc[mt][nt][1]=0.f; acc[mt][nt][2]=0.f; acc[mt][nt][3]=0.f; }

  const _Float16* WlB = Wl + lq * 2048 + wm * 512 + lr * 8;
  const _Float16* SlB = Sl + lq * 1024 + wn * 512 + lr * 8;

  for (int chunk = 0; chunk < NCHUNK; ++chunk) {
    // ---- stage: combine prefetched corners, write S and W tiles ----
    f16x8 s = v0 * sp8((_Float16)w4r.x) + v1 * sp8((_Float16)w4r.y)
            + v2 * sp8((_Float16)w4r.z) + v3 * sp8((_Float16)w4r.w);
    *(f16x8*)(Sl + ((cg * 128 + p) << 3)) = s;
    ((uint4*)Wl)[tid]       = wv0;
    ((uint4*)Wl)[512 + tid] = wv1;
    __syncthreads();

    // ---- prefetch chunk+1 (loads issue; consumed next iter) ----
    if (chunk + 1 < NCHUNK) {
      int nc = chunk + 1;
      int midx = (nc >> 3) * 128 + p;
      int4 px = mi4[midx]; w4r = mw4[midx];
      int cb8 = ((nc & 7) * 32 + cg * 8) >> 3;
      v0 = gin[px.x * 32 + cb8]; v1 = gin[px.y * 32 + cb8];
      v2 = gin[px.z * 32 + cb8]; v3 = gin[px.w * 32 + cb8];
      wv0 = wg4[nc * 1024 + tid]; wv1 = wg4[nc * 1024 + 512 + tid];
    }

    // ---- compute: 16 MFMA per wave ----
    f16x8 afr[4];
#pragma unroll
    for (int mt = 0; mt < 4; ++mt) afr[mt] = *(const f16x8*)(WlB + mt * 128);
#pragma unroll
    for (int nt = 0; nt < 4; ++nt) {
      f16x8 bfr = *(const f16x8*)(SlB + nt * 128);
#pragma unroll
      for (int mt = 0; mt < 4; ++mt)
        acc[mt][nt] = __builtin_amdgcn_mfma_f32_16x16x32_f16(afr[mt], bfr, acc[mt][nt], 0, 0, 0);
    }
    __syncthreads();
  }

  // ---- epilogue: bias + store ----
  const int pbase = rp * 128 + wn * 64 + lr;
#pragma unroll
  for (int mt = 0; mt < 4; ++mt) {
#pragma unroll
    for (int reg = 0; reg < 4; ++reg) {
      int o = wm * 64 + mt * 16 + lq * 4 + reg;
      float bv = bias_l[o];
      float* op = out + ((size_t)(b * 256 + o)) * 4096 + pbase;
#pragma unroll
      for (int nt = 0; nt < 4; ++nt)
        op[nt * 16] = acc[mt][nt][reg] + bv;
    }
  }
}

extern "C" void kernel_launch(void* const* d_in, const int* in_sizes, int n_in,
                              void* d_out, int out_size, void* d_ws, size_t ws_size,
                              hipStream_t stream) {
  const float* inp    = (const float*)d_in[0];
  const float* offset = (const float*)d_in[1];
  const float* mask   = (const float*)d_in[2];
  const float* weight = (const float*)d_in[3];
  const float* bias   = (const float*)d_in[4];
  float* out = (float*)d_out;

  _Float16* inh = (_Float16*)d_ws;                       // 16.78 MB
  _Float16* wgh = inh + (size_t)Bb * HW * Cc;            // +1.18 MB

  hipLaunchKernelGGL(nchw_to_nhwc_f16, dim3(64, Bb), dim3(256), 0, stream, inp, inh);
  hipLaunchKernelGGL(wcvt, dim3(2304), dim3(256), 0, stream, weight, wgh);
  hipLaunchKernelGGL(dcn_mfma, dim3(32, Bb), dim3(512), 0, stream,
                     inh, wgh, offset, mask, bias, out);
}

// Round 3
// 185.353 us; speedup vs baseline: 4.3290x; 1.1345x over previous
//
#include <hip/hip_runtime.h>

typedef _Float16 f16x8 __attribute__((ext_vector_type(8)));
typedef float    f32x4 __attribute__((ext_vector_type(4)));

namespace {
constexpr int Bb = 8, Cc = 256, Oo = 256;
constexpr int HW = 4096;                 // 64x64
constexpr int NCHUNK = 72;               // 2304 / 32
constexpr int SROW = 40;                 // Sl row stride (f16), pad 32->40
}

__device__ inline f16x8 sp8(_Float16 x) { f16x8 r = {x,x,x,x,x,x,x,x}; return r; }

// ---------- pre-kernel 1: NCHW fp32 -> NHWC fp16, no LDS ----------
// thread = (32 px) x (8 c8-slots); 4 c8 iterations -> 32 c8 groups = 256 ch
__global__ __launch_bounds__(256)
void nchw_to_nhwc_f16(const float* __restrict__ in, _Float16* __restrict__ outh) {
  const int tid = threadIdx.x;
  const int b   = blockIdx.y;
  const int px  = blockIdx.x * 32 + (tid >> 3);
  const int c8s = tid & 7;
  const float* src = in + (size_t)b * Cc * HW + px;
  _Float16*    dst = outh + ((size_t)b * HW + px) * Cc;
#pragma unroll
  for (int q = 0; q < 4; ++q) {
    int c8 = q * 8 + c8s;
    f16x8 v;
#pragma unroll
    for (int j = 0; j < 8; ++j)
      v[j] = (_Float16)src[(size_t)(c8 * 8 + j) * HW];
    *(f16x8*)(dst + c8 * 8) = v;
  }
}

// ---------- pre-kernel 2: weight fp32 [O][C][9] -> fp16 [chunk][kq][o][k8] ----------
// K = tap*256 + c ; one f16x8 (8 consecutive K, same tap) per thread
__global__ __launch_bounds__(256)
void wcvt(const float* __restrict__ w, _Float16* __restrict__ wh) {
  int t   = blockIdx.x * 256 + threadIdx.x;   // 0..73727
  int o   = t & 255;
  int ckq = t >> 8;                           // 0..287 = chunk*4 + kq
  int Kb  = ckq * 8;
  const float* s = w + (size_t)o * 2304;
  f16x8 v;
#pragma unroll
  for (int k8 = 0; k8 < 8; ++k8) {
    int K = Kb + k8;
    int tap = K >> 8, c = K & 255;
    v[k8] = (_Float16)s[c * 9 + tap];
  }
  *(f16x8*)(wh + (size_t)t * 8) = v;
}

// ---------- main kernel: 256(o) x 128(p) tile, fp16 MFMA implicit GEMM ----------
// gather lanes: 4 consecutive lanes = same pixel, contiguous 64 B -> 16 lines/inst
__global__ __launch_bounds__(512, 2)
void dcn_mfma(const _Float16* __restrict__ inh,   // [B][4096][256] fp16 NHWC
              const _Float16* __restrict__ wgh,   // [72][4][256][8] fp16
              const float* __restrict__ offset,
              const float* __restrict__ mask,
              const float* __restrict__ bias,
              float* __restrict__ out) {
  __shared__ __align__(16) _Float16 Wl[2][8192];        // 32 KB
  __shared__ __align__(16) _Float16 Sl[2][128 * SROW];  // 20 KB

  const int tid = threadIdx.x;
  const int rp  = blockIdx.x;   // 0..31 : 2 output rows
  const int b   = blockIdx.y;   // 0..7

  // sampling role: pos in [0,128), cg in [0,4) (8 channels each)
  const int pos = tid >> 2, cg = tid & 3;
  const int ho  = rp * 2 + (pos >> 6), wo = pos & 63;
  // MFMA role
  const int lane = tid & 63, wid = tid >> 6;
  const int wm = wid >> 1, wn = wid & 1;          // wave tile 64(o) x 64(p)
  const int lq = lane >> 4, lr = lane & 15;

  const f16x8* gin = (const f16x8*)(inh + (size_t)b * HW * Cc);
  const uint4* wg4 = (const uint4*)wgh;

  int4   mi;          // clipped corner pixel indices (register metadata)
  float4 mwt;         // corner weights (validity+mask folded)
  f16x8  v0, v1, v2, v3;
  uint4  wv0, wv1;

  auto compute_md = [&](int tap) {
    float offy = offset[(((size_t)b * 18 + 2 * tap)     * 64 + ho) * 64 + wo];
    float offx = offset[(((size_t)b * 18 + 2 * tap + 1) * 64 + ho) * 64 + wo];
    float m    = mask  [(((size_t)b * 9  + tap)         * 64 + ho) * 64 + wo];
    int ki = tap / 3, kj = tap % 3;
    float y = offy + (float)(ho - 1 + ki);
    float x = offx + (float)(wo - 1 + kj);
    float y0f = floorf(y), x0f = floorf(x);
    float ly = y - y0f, lx = x - x0f;
    float hy = 1.f - ly, hx = 1.f - lx;
    int y0 = (int)y0f, x0 = (int)x0f;
    int y1 = y0 + 1, x1 = x0 + 1;
    bool vy0 = (unsigned)y0 < 64u, vy1 = (unsigned)y1 < 64u;
    bool vx0 = (unsigned)x0 < 64u, vx1 = (unsigned)x1 < 64u;
    int cy0 = min(max(y0, 0), 63), cy1 = min(max(y1, 0), 63);
    int cx0 = min(max(x0, 0), 63), cx1 = min(max(x1, 0), 63);
    mwt.x = (vy0 && vx0) ? hy * hx * m : 0.f;
    mwt.y = (vy0 && vx1) ? hy * lx * m : 0.f;
    mwt.z = (vy1 && vx0) ? ly * hx * m : 0.f;
    mwt.w = (vy1 && vx1) ? ly * lx * m : 0.f;
    mi = make_int4(cy0 * 64 + cx0, cy0 * 64 + cx1, cy1 * 64 + cx0, cy1 * 64 + cx1);
  };

  auto gather = [&](int c) {
    int cb = (c & 7) * 4 + cg;          // f16x8 octet within pixel
    v0 = gin[mi.x * 32 + cb];
    v1 = gin[mi.y * 32 + cb];
    v2 = gin[mi.z * 32 + cb];
    v3 = gin[mi.w * 32 + cb];
    wv0 = wg4[c * 1024 + tid];
    wv1 = wg4[c * 1024 + 512 + tid];
  };

  auto stage = [&](int nb) {
    f16x8 s = v0 * sp8((_Float16)mwt.x) + v1 * sp8((_Float16)mwt.y)
            + v2 * sp8((_Float16)mwt.z) + v3 * sp8((_Float16)mwt.w);
    *(f16x8*)(&Sl[nb][pos * SROW + cg * 8]) = s;
    ((uint4*)&Wl[nb][0])[tid]       = wv0;
    ((uint4*)&Wl[nb][0])[512 + tid] = wv1;
  };

  f32x4 acc[4][4];
#pragma unroll
  for (int mt = 0; mt < 4; ++mt)
#pragma unroll
    for (int nt = 0; nt < 4; ++nt) {
      acc[mt][nt][0] = 0.f; acc[mt][nt][1] = 0.f;
      acc[mt][nt][2] = 0.f; acc[mt][nt][3] = 0.f;
    }

  // prologue
  compute_md(0);
  gather(0);
  stage(0);
  __syncthreads();

  for (int c = 0; c < NCHUNK; ++c) {
    const int cur = c & 1;
    // issue next chunk's gathers early; MFMA below covers their latency
    if (c + 1 < NCHUNK) {
      if (((c + 1) & 7) == 0) compute_md((c + 1) >> 3);
      gather(c + 1);
    }
    const _Float16* WlB = &Wl[cur][lq * 2048 + (wm * 64 + lr) * 8];
    const _Float16* SlB = &Sl[cur][(wn * 64 + lr) * SROW + lq * 8];
    f16x8 afr[4];
#pragma unroll
    for (int mt = 0; mt < 4; ++mt) afr[mt] = *(const f16x8*)(WlB + mt * 128);
#pragma unroll
    for (int nt = 0; nt < 4; ++nt) {
      f16x8 bfr = *(const f16x8*)(SlB + nt * 16 * SROW);
#pragma unroll
      for (int mt = 0; mt < 4; ++mt)
        acc[mt][nt] = __builtin_amdgcn_mfma_f32_16x16x32_f16(afr[mt], bfr, acc[mt][nt], 0, 0, 0);
    }
    if (c + 1 < NCHUNK) stage(cur ^ 1);
    __syncthreads();
  }

  // ---- epilogue: bias + store ----
  const int pbase = rp * 128 + wn * 64 + lr;
#pragma unroll
  for (int mt = 0; mt < 4; ++mt) {
#pragma unroll
    for (int reg = 0; reg < 4; ++reg) {
      int o = wm * 64 + mt * 16 + lq * 4 + reg;
      float bv = bias[o];
      float* op = out + ((size_t)(b * 256 + o)) * 4096 + pbase;
#pragma unroll
      for (int nt = 0; nt < 4; ++nt)
        op[nt * 16] = acc[mt][nt][reg] + bv;
    }
  }
}

extern "C" void kernel_launch(void* const* d_in, const int* in_sizes, int n_in,
                              void* d_out, int out_size, void* d_ws, size_t ws_size,
                              hipStream_t stream) {
  const float* inp    = (const float*)d_in[0];
  const float* offset = (const float*)d_in[1];
  const float* mask   = (const float*)d_in[2];
  const float* weight = (const float*)d_in[3];
  const float* bias   = (const float*)d_in[4];
  float* out = (float*)d_out;

  _Float16* inh = (_Float16*)d_ws;                       // 16.78 MB
  _Float16* wgh = inh + (size_t)Bb * HW * Cc;            // +1.18 MB

  hipLaunchKernelGGL(nchw_to_nhwc_f16, dim3(128, Bb), dim3(256), 0, stream, inp, inh);
  hipLaunchKernelGGL(wcvt, dim3(288), dim3(256), 0, stream, weight, wgh);
  hipLaunchKernelGGL(dcn_mfma, dim3(32, Bb), dim3(512), 0, stream,
                     inh, wgh, offset, mask, bias, out);
}